// Round 2
// baseline (252.027 us; speedup 1.0000x reference)
//
#include <hip/hip_runtime.h>

// Problem constants (match reference setup_inputs)
#define BB   64
#define CIN  2048
#define COUT 2048
#define TT   128

// Sparse compaction geometry:
//   pair  = 32 output channels (4 mask row-blocks)  -> 64 pairs
//   slot  = 16 k values (2 mask col-blocks)         -> 128 slots, keep ~0.57
//   window= 32 slots (512 bytes of a row)           -> 4 windows
//   chunk = 4 slots = one MFMA K=64
#define NPAIR 64
#define NWIN  4
#define SLOTW 32
#define BC_CAP 7680   // max compacted+padded slots (expected ~5100)

typedef int i32x4 __attribute__((ext_vector_type(4)));

__device__ __forceinline__ void async16(char* lds_dst, const char* g_src) {
    __builtin_amdgcn_global_load_lds(
        (const __attribute__((address_space(1))) void*)g_src,
        (__attribute__((address_space(3))) void*)lds_dst,
        16, 0, 0);
}

// --- prep1: spikes -> i8 A[(b*T+t)][c]  (verified path, bid<8192)
//            + 1 meta block (bid==8192): keep bitmasks + offsets scan
__global__ void prep1(const float* __restrict__ spikes,
                      const float* __restrict__ msk,
                      char* __restrict__ A,
                      unsigned long long* __restrict__ bits,
                      unsigned* __restrict__ nchv,
                      unsigned* __restrict__ ofs) {
    int bid = blockIdx.x;
    int tid = threadIdx.x;

    if (bid == 8192) {
        // meta: thread t = (pair p, window w); scan 32 slots each
        __shared__ unsigned snch[256];
        int p = tid >> 2, wdw = tid & 3;
        unsigned long long bm = 0ull;
        for (int s = 0; s < SLOTW; ++s) {
            int kk = wdw * SLOTW + s;
            bool k = false;
#pragma unroll
            for (int i = 0; i < 4; ++i)
#pragma unroll
                for (int jj = 0; jj < 2; ++jj)
                    k |= (msk[(size_t)(p * 32 + i * 8) * CIN + kk * 16 + jj * 8] != 0.f);
            if (k) bm |= 1ull << s;
        }
        bits[tid] = bm;
        unsigned cnt = (unsigned)__popcll(bm);
        unsigned nch = (cnt + 3) >> 2;
        nchv[tid] = nch;
        snch[tid] = nch;
        __syncthreads();
        if (tid == 0) {
            unsigned run = 0;
            for (int i = 0; i < 256; ++i) { ofs[i] = run; run += snch[i] * 4; }
        }
        return;
    }

    // spikes [B][C][T] fp32 -> A[(b*T+t)][c] i8 via LDS transpose (verified)
    __shared__ float tile[64][33];
    int cc = bid & 31;
    int tt = (bid >> 5) & 3;
    int b  = bid >> 7;
    int c0 = cc * 64, t0 = tt * 32;

    int t4 = tid & 7;
    int cr = tid >> 3;
#pragma unroll
    for (int s = 0; s < 2; ++s) {
        int c = cr + s * 32;
        float4 v = *(const float4*)(spikes + ((size_t)b * CIN + c0 + c) * TT + t0 + t4 * 4);
        tile[c][t4 * 4 + 0] = v.x;
        tile[c][t4 * 4 + 1] = v.y;
        tile[c][t4 * 4 + 2] = v.z;
        tile[c][t4 * 4 + 3] = v.w;
    }
    __syncthreads();

    int tw_ = tid >> 4;
    int cq  = tid & 15;
#pragma unroll
    for (int s2 = 0; s2 < 2; ++s2) {
        int tw = tw_ + s2 * 16;
        int packed = 0;
#pragma unroll
        for (int q = 0; q < 4; ++q)
            packed |= ((tile[cq * 4 + q][tw] != 0.f) ? 1 : 0) << (8 * q);
        *(int*)(A + ((size_t)(b * TT) + t0 + tw) * CIN + c0 + cq * 4) = packed;
    }
}

// --- prep2: fill compacted B (frag-ready [slot][col 0..31][16B]) + slot lists
__global__ void prep2(const float* __restrict__ w,
                      const float* __restrict__ msk,
                      const unsigned long long* __restrict__ bits,
                      const unsigned* __restrict__ ofs,
                      const unsigned* __restrict__ nchv,
                      char* __restrict__ Bc,
                      unsigned short* __restrict__ lst) {
    int pw = blockIdx.x;             // p*4 + wdw
    int p = pw >> 2, wdw = pw & 3;
    unsigned long long rem = bits[pw];
    unsigned o = ofs[pw];
    unsigned nslots = nchv[pw] * 4;
    int tid = threadIdx.x;

    for (unsigned j = 0; j < nslots; ++j) {
        int kl = 0;
        bool real = false;
        if (rem) { kl = __ffsll(rem) - 1; rem &= rem - 1ull; real = true; }
        int kk = wdw * SLOTW + kl;   // global k16 slot
        if (tid < 128) {
            int col = tid >> 2, q = tid & 3;
            unsigned pk = 0u;
            if (real) {
                size_t base = (size_t)(p * 32 + col) * CIN + kk * 16 + q * 4;
                float4 a = *(const float4*)(w + base);
                float4 m = *(const float4*)(msk + base);
                int b0 = (int)(char)(int)(a.x * m.x);
                int b1 = (int)(char)(int)(a.y * m.y);
                int b2 = (int)(char)(int)(a.z * m.z);
                int b3 = (int)(char)(int)(a.w * m.w);
                pk = (unsigned)((b0 & 0xFF) | ((b1 & 0xFF) << 8) | ((b2 & 0xFF) << 16) | (b3 << 24));
            }
            *(unsigned*)(Bc + (size_t)(o + j) * 512 + col * 16 + q * 4) = pk;
        }
        if (tid == 0) lst[o + j] = (unsigned short)(real ? kl : 0);
    }
}

// --- Sparse-gather GEMM: BM=128 (one batch), BN=256 (8 pairs), compacted K
//     + LIF scan epilogue in two 128-channel passes + coalesced store ---
__global__ void __launch_bounds__(512, 4)
snn_gemm_scan(const char* __restrict__ A,     // [8192][2048] i8
              const char* __restrict__ Bc,    // compacted [slot][32][16] i8
              const unsigned short* __restrict__ lst,
              const unsigned* __restrict__ ofs,
              const unsigned* __restrict__ nchv,
              const int* __restrict__ scale_exp,
              const int* __restrict__ thr_exp,
              float* __restrict__ out) {      // [B][COUT][T]
    __shared__ __align__(16) union {
        struct {
            char a[128 * 512];                // 64 KB A k-window
            unsigned short l[8 * SLOTW];      // slot lists (local idx)
            unsigned meta[16];                // {ofs, nch} per pair
        } s;
        float c[128 * 132];                   // 67.6 KB scan buffer
    } lds;
    __shared__ unsigned pb[128 * 4];

    const int tid  = threadIdx.x;
    const int lane = tid & 63;
    const int w    = tid >> 6;
    const int wr   = w >> 2;    // 0..1: row half (4 m-frags)
    const int wp   = w & 3;     // 0..3: pair-pair (2 pairs each)

    // bid = nt*64 + b: blocks sharing batch b are co-XCD (A panel L2-resident);
    // Bc (~2.4 MB total) is L2-resident on every XCD.
    const int bid = blockIdx.x;
    const int b  = bid & 63;
    const int nt = bid >> 6;          // 0..7
    const int m0 = b * TT;
    const int p0 = nt * 8;            // global pair base

    const int mrow = lane & 15, kc = lane >> 4;

    i32x4 acc[4][2][2] = {};          // [m-frag][pair][col-frag]

    for (int wdw = 0; wdw < NWIN; ++wdw) {
        __syncthreads();              // prior window reads done before overwrite
        // stage per-pair meta {ofs, nch}
        if (tid < 16) {
            int pl = tid >> 1;
            const unsigned* src = (tid & 1) ? nchv : ofs;
            lds.s.meta[tid] = src[(p0 + pl) * 4 + wdw];
        }
        // stage slot lists: fixed 32 entries per pair (tail never read)
        if (tid < 128) {
            int pl = tid >> 4, e2 = tid & 15;
            unsigned o = ofs[(p0 + pl) * 4 + wdw];
            *(unsigned*)&lds.s.l[pl * SLOTW + e2 * 2] =
                *(const unsigned*)(lst + o + e2 * 2);
        }
        // stage A window: 128 rows x 512 B, source XOR-swizzled, dest linear
#pragma unroll
        for (int i = 0; i < 8; ++i) {
            int f = i * 512 + tid;
            int row = f >> 5, g0 = f & 31;
            int src = (g0 & ~7) | ((g0 & 7) ^ (row & 7));
            async16((char*)lds.s.a + (size_t)f * 16,
                    A + (size_t)(m0 + row) * CIN + wdw * 512 + src * 16);
        }
        __syncthreads();              // full drain (vmcnt + lgkm)

#pragma unroll
        for (int pi = 0; pi < 2; ++pi) {
            const int pl = wp * 2 + pi;
            const unsigned o   = lds.s.meta[pl * 2];
            const unsigned nch = lds.s.meta[pl * 2 + 1];
            const unsigned short* Lp = &lds.s.l[pl * SLOTW];
            for (unsigned c = 0; c < nch; ++c) {
                const int kk = (int)Lp[c * 4 + kc];   // local slot, broadcast/16
                const char* bp = Bc + (size_t)(o + c * 4 + kc) * 512 + mrow * 16;
                i32x4 bv0 = *(const i32x4*)bp;        // cols 0..15
                i32x4 bv1 = *(const i32x4*)(bp + 256);// cols 16..31
#pragma unroll
                for (int mf = 0; mf < 4; ++mf) {
                    int row = wr * 64 + mf * 16 + mrow;
                    i32x4 av = *(const i32x4*)((const char*)lds.s.a +
                                  row * 512 + ((kk ^ (row & 7)) << 4));
                    acc[mf][pi][0] = __builtin_amdgcn_mfma_i32_16x16x64_i8(
                        av, bv0, acc[mf][pi][0], 0, 0, 0);
                    acc[mf][pi][1] = __builtin_amdgcn_mfma_i32_16x16x64_i8(
                        av, bv1, acc[mf][pi][1], 0, 0, 0);
                }
            }
        }
    }

    // ---- Epilogue: LIF scan, two passes of 128 channels ----
    const float thr = exp2f((float)thr_exp[0]);
#pragma unroll
    for (int P = 0; P < 2; ++P) {
        __syncthreads();
        if ((wp >> 1) == P) {
            const int rb = (lane >> 4) * 4;
            const int cb = lane & 15;
            const int cbase = (wp & 1) * 64;
#pragma unroll
            for (int mf = 0; mf < 4; ++mf)
#pragma unroll
                for (int pi = 0; pi < 2; ++pi)
#pragma unroll
                    for (int cf = 0; cf < 2; ++cf)
#pragma unroll
                        for (int r = 0; r < 4; ++r)
                            lds.c[(wr * 64 + mf * 16 + rb + r) * 132 +
                                  cbase + pi * 32 + cf * 16 + cb] =
                                (float)acc[mf][pi][cf][r];
        }
        __syncthreads();

        if (tid < 128) {
            const float scale = exp2f((float)scale_exp[nt * 256 + P * 128 + tid]);
            float a = 0.f;
#pragma unroll
            for (int q = 0; q < 4; ++q) {
                unsigned bq = 0u;
#pragma unroll 8
                for (int j = 0; j < 32; ++j) {
                    a += lds.c[(q * 32 + j) * 132 + tid] * scale;
                    unsigned sp = (a >= thr) ? 1u : 0u;
                    if (sp) a = 0.f;
                    bq |= sp << j;
                }
                pb[tid * 4 + q] = bq;
            }
        }
        __syncthreads();

        // coalesced float4 stores: out[b][nt*256 + P*128 + co][t]
        const int t4 = tid & 31, u = tid >> 5;
#pragma unroll
        for (int s2 = 0; s2 < 8; ++s2) {
            int co = s2 * 16 + u;
            unsigned wb  = pb[co * 4 + (t4 >> 3)];
            unsigned nib = (wb >> ((t4 & 7) * 4)) & 0xFu;
            float4 v;
            v.x = (float)(nib & 1u);
            v.y = (float)((nib >> 1) & 1u);
            v.z = (float)((nib >> 2) & 1u);
            v.w = (float)((nib >> 3) & 1u);
            *(float4*)(out + (size_t)(b * COUT + nt * 256 + P * 128 + co) * TT
                       + t4 * 4) = v;
        }
    }
}

extern "C" void kernel_launch(void* const* d_in, const int* in_sizes, int n_in,
                              void* d_out, int out_size, void* d_ws, size_t ws_size,
                              hipStream_t stream) {
    const float* spikes  = (const float*)d_in[0];
    const float* weights = (const float*)d_in[1];
    const float* mask    = (const float*)d_in[2];
    const int*   scale_e = (const int*)d_in[3];
    const int*   thr_e   = (const int*)d_in[4];
    float* out = (float*)d_out;

    // workspace layout (total 20,729,856 B <= previous 20 MB usage):
    char* ws = (char*)d_ws;
    char*               Ai8  = ws;                                     // 16 MB
    char*               Bc   = ws + 16777216;                          // 3.75 MB arena
    unsigned short*     lstp = (unsigned short*)(ws + 20709376);       // 16 KB
    unsigned*           ofsp = (unsigned*)(ws + 20725760);             // 1 KB
    unsigned*           nchp = (unsigned*)(ws + 20726784);             // 1 KB
    unsigned long long* bitp = (unsigned long long*)(ws + 20727808);   // 2 KB

    prep1<<<BB * 4 * 32 + 1, 256, 0, stream>>>(spikes, mask, Ai8, bitp, nchp, ofsp);
    prep2<<<NPAIR * NWIN, 256, 0, stream>>>(weights, mask, bitp, ofsp, nchp, Bc, lstp);
    snn_gemm_scan<<<8 * BB, 512, 0, stream>>>(Ai8, Bc, lstp, ofsp, nchp,
                                              scale_e, thr_e, out);
}

// Round 3
// 204.272 us; speedup vs baseline: 1.2338x; 1.2338x over previous
//
#include <hip/hip_runtime.h>

// Problem constants (match reference setup_inputs)
#define BB   64
#define CIN  2048
#define COUT 2048
#define TT   128

// Sparse compaction geometry:
//   pair  = 32 output channels (4 mask row-blocks)  -> 64 pairs
//   slot  = 16 k values (2 mask col-blocks)         -> 128 slots, keep ~0.57
//   window= 32 slots (512 bytes of a row)           -> 4 windows
//   chunk = 4 slots = one MFMA K=64
#define NPAIR 64
#define NWIN  4
#define SLOTW 32
#define BC_CAP 7680   // max compacted+padded slots (expected ~5100)

typedef int i32x4 __attribute__((ext_vector_type(4)));

__device__ __forceinline__ void async16(char* lds_dst, const char* g_src) {
    __builtin_amdgcn_global_load_lds(
        (const __attribute__((address_space(1))) void*)g_src,
        (__attribute__((address_space(3))) void*)lds_dst,
        16, 0, 0);
}

// --- prep1: spikes -> i8 A[(b*T+t)][c]  (verified path, bid<8192)
//            + 256 ballot blocks (bid>=8192): keep-bit table kb[256][4] u64
__global__ void prep1(const float* __restrict__ spikes,
                      const float* __restrict__ msk,
                      char* __restrict__ A,
                      unsigned long long* __restrict__ kb) {
    int bid = blockIdx.x;
    int tid = threadIdx.x;

    if (bid >= 8192) {
        // block rb: thread cb reads one representative element of mask
        // block (rb, cb) (mask is 8x8-constant) -> ballot into kb[rb][w]
        int rb = bid - 8192;
        bool keep = (msk[(size_t)(rb * 8) * CIN + tid * 8] != 0.f);
        unsigned long long m = __ballot(keep);
        if ((tid & 63) == 0) kb[rb * 4 + (tid >> 6)] = m;
        return;
    }

    // spikes [B][C][T] fp32 -> A[(b*T+t)][c] i8 via LDS transpose (verified)
    __shared__ float tile[64][33];
    int cc = bid & 31;
    int tt = (bid >> 5) & 3;
    int b  = bid >> 7;
    int c0 = cc * 64, t0 = tt * 32;

    int t4 = tid & 7;
    int cr = tid >> 3;
#pragma unroll
    for (int s = 0; s < 2; ++s) {
        int c = cr + s * 32;
        float4 v = *(const float4*)(spikes + ((size_t)b * CIN + c0 + c) * TT + t0 + t4 * 4);
        tile[c][t4 * 4 + 0] = v.x;
        tile[c][t4 * 4 + 1] = v.y;
        tile[c][t4 * 4 + 2] = v.z;
        tile[c][t4 * 4 + 3] = v.w;
    }
    __syncthreads();

    int tw_ = tid >> 4;
    int cq  = tid & 15;
#pragma unroll
    for (int s2 = 0; s2 < 2; ++s2) {
        int tw = tw_ + s2 * 16;
        int packed = 0;
#pragma unroll
        for (int q = 0; q < 4; ++q)
            packed |= ((tile[cq * 4 + q][tw] != 0.f) ? 1 : 0) << (8 * q);
        *(int*)(A + ((size_t)(b * TT) + t0 + tw) * CIN + c0 + cq * 4) = packed;
    }
}

// --- prep2: redundant per-block meta (bm/ofs/nch from kb, ~2us, L2-hot)
//            + fill compacted B (frag-ready [slot][col 0..31][16B]) + slot lists
__global__ void prep2(const float* __restrict__ w,
                      const float* __restrict__ msk,
                      const unsigned long long* __restrict__ kb,
                      char* __restrict__ Bc,
                      unsigned short* __restrict__ lst,
                      unsigned* __restrict__ ofs_g,
                      unsigned* __restrict__ nch_g) {
    __shared__ unsigned sbm[256];
    __shared__ unsigned snch[256];
    __shared__ unsigned sofs[256];
    const int tid = threadIdx.x;
    const int pw_self = blockIdx.x;

    // thread t computes slot-mask for (pair t>>2, window t&3):
    // or-reduce the 4 row-block words, collapse bit pairs (2 col-blocks/slot)
    {
        int p = tid >> 2, wdw = tid & 3;
        unsigned long long r = kb[(4 * p + 0) * 4 + wdw] | kb[(4 * p + 1) * 4 + wdw] |
                               kb[(4 * p + 2) * 4 + wdw] | kb[(4 * p + 3) * 4 + wdw];
        unsigned long long t2 = r | (r >> 1);
        unsigned bm = 0u;
#pragma unroll
        for (int s = 0; s < 32; ++s)
            bm |= (unsigned)((t2 >> (2 * s)) & 1ull) << s;
        sbm[tid]  = bm;
        snch[tid] = (unsigned)((__popc(bm) + 3) >> 2);
    }
    __syncthreads();
    if (tid == 0) {
        unsigned run = 0;
#pragma unroll 4
        for (int i = 0; i < 256; ++i) { sofs[i] = run; run += snch[i] * 4; }
        ofs_g[pw_self] = sofs[pw_self];
        nch_g[pw_self] = snch[pw_self];
    }
    __syncthreads();

    const int p = pw_self >> 2, wdw = pw_self & 3;
    unsigned rem = sbm[pw_self];
    const unsigned o = sofs[pw_self];
    const unsigned nslots = snch[pw_self] * 4;

    for (unsigned j = 0; j < nslots; ++j) {
        int kl = 0;
        bool real = false;
        if (rem) { kl = __ffs(rem) - 1; rem &= rem - 1u; real = true; }
        int kk = wdw * SLOTW + kl;   // global k16 slot
        if (tid < 128) {
            int col = tid >> 2, q = tid & 3;
            unsigned pk = 0u;
            if (real) {
                size_t base = (size_t)(p * 32 + col) * CIN + kk * 16 + q * 4;
                float4 a = *(const float4*)(w + base);
                float4 m = *(const float4*)(msk + base);
                int b0 = (int)(char)(int)(a.x * m.x);
                int b1 = (int)(char)(int)(a.y * m.y);
                int b2 = (int)(char)(int)(a.z * m.z);
                int b3 = (int)(char)(int)(a.w * m.w);
                pk = (unsigned)((b0 & 0xFF) | ((b1 & 0xFF) << 8) | ((b2 & 0xFF) << 16) | (b3 << 24));
            }
            *(unsigned*)(Bc + (size_t)(o + j) * 512 + col * 16 + q * 4) = pk;
        }
        if (tid == 0) lst[o + j] = (unsigned short)(real ? kl : 0);
    }
}

// --- Sparse-gather GEMM: BM=128 (one batch), BN=256 (8 pairs), compacted K
//     + LIF scan epilogue in two 128-channel passes + coalesced store ---
//     (byte-identical structure to round-2 version; isolate the prep fix)
__global__ void __launch_bounds__(512, 4)
snn_gemm_scan(const char* __restrict__ A,     // [8192][2048] i8
              const char* __restrict__ Bc,    // compacted [slot][32][16] i8
              const unsigned short* __restrict__ lst,
              const unsigned* __restrict__ ofs,
              const unsigned* __restrict__ nchv,
              const int* __restrict__ scale_exp,
              const int* __restrict__ thr_exp,
              float* __restrict__ out) {      // [B][COUT][T]
    __shared__ __align__(16) union {
        struct {
            char a[128 * 512];                // 64 KB A k-window
            unsigned short l[8 * SLOTW];      // slot lists (local idx)
            unsigned meta[16];                // {ofs, nch} per pair
        } s;
        float c[128 * 132];                   // 67.6 KB scan buffer
    } lds;
    __shared__ unsigned pb[128 * 4];

    const int tid  = threadIdx.x;
    const int lane = tid & 63;
    const int w    = tid >> 6;
    const int wr   = w >> 2;    // 0..1: row half (4 m-frags)
    const int wp   = w & 3;     // 0..3: pair-pair (2 pairs each)

    // bid = nt*64 + b: blocks sharing batch b are co-XCD (A panel L2-resident);
    // Bc (~2.4 MB total) is L2-resident on every XCD.
    const int bid = blockIdx.x;
    const int b  = bid & 63;
    const int nt = bid >> 6;          // 0..7
    const int m0 = b * TT;
    const int p0 = nt * 8;            // global pair base

    const int mrow = lane & 15, kc = lane >> 4;

    i32x4 acc[4][2][2] = {};          // [m-frag][pair][col-frag]

    for (int wdw = 0; wdw < NWIN; ++wdw) {
        __syncthreads();              // prior window reads done before overwrite
        // stage per-pair meta {ofs, nch}
        if (tid < 16) {
            int pl = tid >> 1;
            const unsigned* src = (tid & 1) ? nchv : ofs;
            lds.s.meta[tid] = src[(p0 + pl) * 4 + wdw];
        }
        // stage slot lists: fixed 32 entries per pair (tail never read)
        if (tid < 128) {
            int pl = tid >> 4, e2 = tid & 15;
            unsigned o = ofs[(p0 + pl) * 4 + wdw];
            *(unsigned*)&lds.s.l[pl * SLOTW + e2 * 2] =
                *(const unsigned*)(lst + o + e2 * 2);
        }
        // stage A window: 128 rows x 512 B, source XOR-swizzled, dest linear
#pragma unroll
        for (int i = 0; i < 8; ++i) {
            int f = i * 512 + tid;
            int row = f >> 5, g0 = f & 31;
            int src = (g0 & ~7) | ((g0 & 7) ^ (row & 7));
            async16((char*)lds.s.a + (size_t)f * 16,
                    A + (size_t)(m0 + row) * CIN + wdw * 512 + src * 16);
        }
        __syncthreads();              // full drain (vmcnt + lgkm)

#pragma unroll
        for (int pi = 0; pi < 2; ++pi) {
            const int pl = wp * 2 + pi;
            const unsigned o   = lds.s.meta[pl * 2];
            const unsigned nch = lds.s.meta[pl * 2 + 1];
            const unsigned short* Lp = &lds.s.l[pl * SLOTW];
            for (unsigned c = 0; c < nch; ++c) {
                const int kk = (int)Lp[c * 4 + kc];   // local slot, broadcast/16
                const char* bp = Bc + (size_t)(o + c * 4 + kc) * 512 + mrow * 16;
                i32x4 bv0 = *(const i32x4*)bp;        // cols 0..15
                i32x4 bv1 = *(const i32x4*)(bp + 256);// cols 16..31
#pragma unroll
                for (int mf = 0; mf < 4; ++mf) {
                    int row = wr * 64 + mf * 16 + mrow;
                    i32x4 av = *(const i32x4*)((const char*)lds.s.a +
                                  row * 512 + ((kk ^ (row & 7)) << 4));
                    acc[mf][pi][0] = __builtin_amdgcn_mfma_i32_16x16x64_i8(
                        av, bv0, acc[mf][pi][0], 0, 0, 0);
                    acc[mf][pi][1] = __builtin_amdgcn_mfma_i32_16x16x64_i8(
                        av, bv1, acc[mf][pi][1], 0, 0, 0);
                }
            }
        }
    }

    // ---- Epilogue: LIF scan, two passes of 128 channels ----
    const float thr = exp2f((float)thr_exp[0]);
#pragma unroll
    for (int P = 0; P < 2; ++P) {
        __syncthreads();
        if ((wp >> 1) == P) {
            const int rb = (lane >> 4) * 4;
            const int cb = lane & 15;
            const int cbase = (wp & 1) * 64;
#pragma unroll
            for (int mf = 0; mf < 4; ++mf)
#pragma unroll
                for (int pi = 0; pi < 2; ++pi)
#pragma unroll
                    for (int cf = 0; cf < 2; ++cf)
#pragma unroll
                        for (int r = 0; r < 4; ++r)
                            lds.c[(wr * 64 + mf * 16 + rb + r) * 132 +
                                  cbase + pi * 32 + cf * 16 + cb] =
                                (float)acc[mf][pi][cf][r];
        }
        __syncthreads();

        if (tid < 128) {
            const float scale = exp2f((float)scale_exp[nt * 256 + P * 128 + tid]);
            float a = 0.f;
#pragma unroll
            for (int q = 0; q < 4; ++q) {
                unsigned bq = 0u;
#pragma unroll 8
                for (int j = 0; j < 32; ++j) {
                    a += lds.c[(q * 32 + j) * 132 + tid] * scale;
                    unsigned sp = (a >= thr) ? 1u : 0u;
                    if (sp) a = 0.f;
                    bq |= sp << j;
                }
                pb[tid * 4 + q] = bq;
            }
        }
        __syncthreads();

        // coalesced float4 stores: out[b][nt*256 + P*128 + co][t]
        const int t4 = tid & 31, u = tid >> 5;
#pragma unroll
        for (int s2 = 0; s2 < 8; ++s2) {
            int co = s2 * 16 + u;
            unsigned wb  = pb[co * 4 + (t4 >> 3)];
            unsigned nib = (wb >> ((t4 & 7) * 4)) & 0xFu;
            float4 v;
            v.x = (float)(nib & 1u);
            v.y = (float)((nib >> 1) & 1u);
            v.z = (float)((nib >> 2) & 1u);
            v.w = (float)((nib >> 3) & 1u);
            *(float4*)(out + (size_t)(b * COUT + nt * 256 + P * 128 + co) * TT
                       + t4 * 4) = v;
        }
    }
}

extern "C" void kernel_launch(void* const* d_in, const int* in_sizes, int n_in,
                              void* d_out, int out_size, void* d_ws, size_t ws_size,
                              hipStream_t stream) {
    const float* spikes  = (const float*)d_in[0];
    const float* weights = (const float*)d_in[1];
    const float* mask    = (const float*)d_in[2];
    const int*   scale_e = (const int*)d_in[3];
    const int*   thr_e   = (const int*)d_in[4];
    float* out = (float*)d_out;

    // workspace layout (total 20,736,000 B < 20 MiB floor used in round 0):
    char* ws = (char*)d_ws;
    char*               Ai8  = ws;                                     // 16 MB
    char*               Bc   = ws + 16777216;                          // 3.75 MB arena
    unsigned short*     lstp = (unsigned short*)(ws + 20709376);       // 16 KB
    unsigned*           ofsp = (unsigned*)(ws + 20725760);             // 1 KB
    unsigned*           nchp = (unsigned*)(ws + 20726784);             // 1 KB
    unsigned long long* kbp  = (unsigned long long*)(ws + 20727808);   // 8 KB

    prep1<<<BB * 4 * 32 + 256, 256, 0, stream>>>(spikes, mask, Ai8, kbp);
    prep2<<<NPAIR * NWIN, 256, 0, stream>>>(weights, mask, kbp, Bc, lstp, ofsp, nchp);
    snn_gemm_scan<<<8 * BB, 512, 0, stream>>>(Ai8, Bc, lstp, ofsp, nchp,
                                              scale_e, thr_e, out);
}